// Round 3
// baseline (182.610 us; speedup 1.0000x reference)
//
#include <hip/hip_runtime.h>
#include <stdint.h>

// ---------------------------------------------------------------------------
// MHA forward: fp32 in/out, internal bf16, fp32 accumulate.
//   B=4 S=2048 D=512 H=8 DH=64
//   pipeline (3 kernels, convert fused into GEMM staging):
//     gemm_qkv : fp32 A,W -> reg-convert bf16 -> dbuf LDS -> MFMA -> qp/kp/vp
//     attn     : flash attention (64-key dbuf tiles, 1 barrier/tile)
//     gemm_out : bf16 A via global_load_lds, fp32 Wo reg-converted, fp32 out
// MFMA 16x16x32 bf16 layouts (HW-verified per guide):
//   A-frag: lane holds A[m=lane&15][k=(lane>>4)*8 + j], j=0..7 (contiguous)
//   B-frag: lane holds B[k=(lane>>4)*8 + j][n=lane&15]
//   C/D   : lane reg r holds D[row=(lane>>4)*4 + r][col=lane&15]
// ---------------------------------------------------------------------------

typedef __attribute__((ext_vector_type(8))) short short8;
typedef __attribute__((ext_vector_type(4))) float f32x4;

#define MFMA16(a, b, c) __builtin_amdgcn_mfma_f32_16x16x32_bf16(a, b, c, 0, 0, 0)

#define SCALE_LOG2 0.18033688011112042f
#define FIXED_M    32.0f
#define MASKED_E2  -200.0f   // exp2(-200) == 0.0f exactly

__device__ __forceinline__ unsigned short f2bf(float f) {
    unsigned int x = __float_as_uint(f);
    unsigned int r = (x + 0x7fffu + ((x >> 16) & 1u)) >> 16;  // RNE
    return (unsigned short)r;
}
// packed fp32x2 -> bf16x2 (RNE), single HW instruction
__device__ __forceinline__ unsigned int cvt_pk_bf16(float lo, float hi) {
    unsigned int r;
    asm("v_cvt_pk_bf16_f32 %0, %1, %2" : "=v"(r) : "v"(lo), "v"(hi));
    return r;
}
__device__ __forceinline__ short8 load8(const unsigned short* p) {
    return *reinterpret_cast<const short8*>(p);
}
__device__ __forceinline__ float4 ld4(const float* p) {
    return *reinterpret_cast<const float4*>(p);
}
// async 16B global -> LDS DMA (lane l lands at lds + l*16)
__device__ __forceinline__ void gload_lds16(const unsigned short* g, unsigned short* l) {
    __builtin_amdgcn_global_load_lds(
        (const __attribute__((address_space(1))) unsigned int*)g,
        (__attribute__((address_space(3))) unsigned int*)l, 16, 0, 0);
}
// convert 8 staged fp32 (two float4) to 8 bf16 and ds_write_b128
__device__ __forceinline__ void cvt_write8(unsigned short* dst, float4 v0, float4 v1) {
    uint4 d;
    d.x = cvt_pk_bf16(v0.x, v0.y);
    d.y = cvt_pk_bf16(v0.z, v0.w);
    d.z = cvt_pk_bf16(v1.x, v1.y);
    d.w = cvt_pk_bf16(v1.z, v1.w);
    *reinterpret_cast<uint4*>(dst) = d;
}

// ---------------------------------------------------------------------------
// QKV NT GEMM with fused fp32->bf16 conversion.
// C[i][j] = sum_k A[i][k]*W[j][k] + bias[j];  A [8192,512] fp32, W [512,512] fp32.
// 128x128 tile, BK=64, 256 thr = 4 waves (2x2 of 64x64 sub-tiles).
// Staging: reg-staged (load float4 pairs one K-step ahead, v_cvt_pk_bf16_f32,
//   ds_write_b128), double-buffered LDS, ONE barrier per K-step.
// LDS layout: slot s = r*8+c holds global chunk g = c ^ (r&7) of row r
//   (XOR swizzle) -> frag ds_read_b128 2-way conflict (free).
// XCD swizzle: 4 col-blocks of an A row-strip on the same XCD (L2 reuse).
// Output (z in {0,1,2}): qp/kp/vp [B,H,S,64] bf16 scatter.
// ---------------------------------------------------------------------------
__global__ __launch_bounds__(256)
void gemm_qkv(const float* __restrict__ Aq, const float* __restrict__ Ak,
              const float* __restrict__ Av,
              const float* __restrict__ Wqf, const float* __restrict__ Wkf,
              const float* __restrict__ Wvf,
              const float* __restrict__ bq, const float* __restrict__ bk,
              const float* __restrict__ bv,
              unsigned short* __restrict__ outall)
{
    __shared__ unsigned short As[2][8192];
    __shared__ unsigned short Bs[2][8192];

    const int z = blockIdx.y;
    const float* A    = (z == 0) ? Aq  : (z == 1) ? Ak  : Av;
    const float* W    = (z == 0) ? Wqf : (z == 1) ? Wkf : Wvf;
    const float* bias = (z == 0) ? bq  : (z == 1) ? bk  : bv;
    unsigned short* out = outall + (long)z * 4194304;

    const int f    = blockIdx.x;       // 0..255
    const int xcd  = f & 7;
    const int slot = f >> 3;
    const int col0 = (slot & 3) * 128;
    const int row0 = ((slot >> 2) * 8 + xcd) * 128;

    const int tid  = threadIdx.x;
    const int lane = tid & 63;
    const int w    = tid >> 6;
    const int quad = lane >> 4;
    const int nlow = lane & 15;
    const int wm   = w >> 1, wn = w & 1;

    // staging descriptors: slot s = i*256+tid -> r=s>>3, c=s&7, g=c^(r&7)
    const float* ag[4];
    const float* wg[4];
    int sw[4];                          // LDS elem offset = s*8
#pragma unroll
    for (int i = 0; i < 4; i++) {
        const int s = i * 256 + tid;
        const int r = s >> 3;
        const int kg = (s & 7) ^ (r & 7);
        ag[i] = A + (long)(row0 + r) * 512 + kg * 8;
        wg[i] = W + (long)(col0 + r) * 512 + kg * 8;
        sw[i] = s * 8;
    }

    f32x4 acc[4][4];
#pragma unroll
    for (int t = 0; t < 4; t++)
#pragma unroll
        for (int g = 0; g < 4; g++) acc[t][g] = (f32x4){0.f, 0.f, 0.f, 0.f};

    float4 ra[4][2], rw[4][2];
    // prologue: stage K-step 0
#pragma unroll
    for (int i = 0; i < 4; i++) {
        ra[i][0] = ld4(ag[i]);     ra[i][1] = ld4(ag[i] + 4);
        rw[i][0] = ld4(wg[i]);     rw[i][1] = ld4(wg[i] + 4);
    }
#pragma unroll
    for (int i = 0; i < 4; i++) {
        cvt_write8(&As[0][sw[i]], ra[i][0], ra[i][1]);
        cvt_write8(&Bs[0][sw[i]], rw[i][0], rw[i][1]);
    }
    __syncthreads();

    int cur = 0;
    for (int k0 = 64; k0 <= 512; k0 += 64) {
        const bool more = (k0 < 512);
        if (more) {
#pragma unroll
            for (int i = 0; i < 4; i++) {
                ra[i][0] = ld4(ag[i] + k0);     ra[i][1] = ld4(ag[i] + k0 + 4);
                rw[i][0] = ld4(wg[i] + k0);     rw[i][1] = ld4(wg[i] + k0 + 4);
            }
        }
        // compute on buffer cur (frags loaded per-kc to cap liveness)
#pragma unroll
        for (int kc = 0; kc < 2; kc++) {
            short8 af[4], bfr[4];
#pragma unroll
            for (int t = 0; t < 4; t++) {
                const int rowa = wm * 64 + t * 16 + nlow;
                const int rowb = wn * 64 + t * 16 + nlow;
                const int ca = (kc * 4 + quad) ^ (nlow & 7);
                af[t]  = load8(&As[cur][(rowa * 8 + ca) * 8]);
                bfr[t] = load8(&Bs[cur][(rowb * 8 + ca) * 8]);
            }
#pragma unroll
            for (int t = 0; t < 4; t++)
#pragma unroll
                for (int g = 0; g < 4; g++)
                    acc[t][g] = MFMA16(af[t], bfr[g], acc[t][g]);
        }
        if (more) {
#pragma unroll
            for (int i = 0; i < 4; i++) {
                cvt_write8(&As[cur ^ 1][sw[i]], ra[i][0], ra[i][1]);
                cvt_write8(&Bs[cur ^ 1][sw[i]], rw[i][0], rw[i][1]);
            }
        }
        __syncthreads();
        cur ^= 1;
    }

    // epilogue: scatter to [B,H,S,64] bf16
#pragma unroll
    for (int g = 0; g < 4; g++) {
        const int j = col0 + wn * 64 + g * 16 + nlow;
        const float bj = bias[j];
        const int h = j >> 6, dh = j & 63;
#pragma unroll
        for (int t = 0; t < 4; t++) {
#pragma unroll
            for (int r = 0; r < 4; r++) {
                const int i = row0 + wm * 64 + t * 16 + quad * 4 + r;
                const int b = i >> 11, s = i & 2047;
                out[(((b * 8 + h) * 2048) + s) * 64 + dh] = f2bf(acc[t][g][r] + bj);
            }
        }
    }
}

// ---------------------------------------------------------------------------
// Out-proj NT GEMM: A = ao bf16 [8192,512] via global_load_lds (pre-swizzled
// source), W = Wo fp32 reg-converted. fp32 output. dbuf LDS, 1 barrier/step.
// ---------------------------------------------------------------------------
__global__ __launch_bounds__(256)
void gemm_out(const unsigned short* __restrict__ Aao,
              const float* __restrict__ Wof, const float* __restrict__ bo,
              float* __restrict__ outp)
{
    __shared__ unsigned short As[2][8192];
    __shared__ unsigned short Bs[2][8192];

    const int f    = blockIdx.x;       // 0..255
    const int xcd  = f & 7;
    const int slot = f >> 3;
    const int col0 = (slot & 3) * 128;
    const int row0 = ((slot >> 2) * 8 + xcd) * 128;

    const int tid  = threadIdx.x;
    const int lane = tid & 63;
    const int w    = tid >> 6;
    const int quad = lane >> 4;
    const int nlow = lane & 15;
    const int wm   = w >> 1, wn = w & 1;

    const unsigned short* ag[4];
    unsigned short* la[2][4];
    const float* wg[4];
    int sw[4];
#pragma unroll
    for (int i = 0; i < 4; i++) {
        const int s = i * 256 + tid;
        const int r = s >> 3;
        const int kg = (s & 7) ^ (r & 7);
        ag[i] = Aao + (long)(row0 + r) * 512 + kg * 8;
        wg[i] = Wof + (long)(col0 + r) * 512 + kg * 8;
        const int ldso = i * 2048 + (w << 9);      // wave-uniform DMA base
        la[0][i] = &As[0][ldso];
        la[1][i] = &As[1][ldso];
        sw[i] = s * 8;
    }

    f32x4 acc[4][4];
#pragma unroll
    for (int t = 0; t < 4; t++)
#pragma unroll
        for (int g = 0; g < 4; g++) acc[t][g] = (f32x4){0.f, 0.f, 0.f, 0.f};

    float4 rw[4][2];
    // prologue: stage K-step 0
#pragma unroll
    for (int i = 0; i < 4; i++) {
        gload_lds16(ag[i], la[0][i]);
        rw[i][0] = ld4(wg[i]);  rw[i][1] = ld4(wg[i] + 4);
    }
#pragma unroll
    for (int i = 0; i < 4; i++)
        cvt_write8(&Bs[0][sw[i]], rw[i][0], rw[i][1]);
    __syncthreads();

    int cur = 0;
    for (int k0 = 64; k0 <= 512; k0 += 64) {
        const bool more = (k0 < 512);
        if (more) {
#pragma unroll
            for (int i = 0; i < 4; i++) {
                gload_lds16(ag[i] + k0, la[cur ^ 1][i]);
                rw[i][0] = ld4(wg[i] + k0);  rw[i][1] = ld4(wg[i] + k0 + 4);
            }
        }
#pragma unroll
        for (int kc = 0; kc < 2; kc++) {
            short8 af[4], bfr[4];
#pragma unroll
            for (int t = 0; t < 4; t++) {
                const int rowa = wm * 64 + t * 16 + nlow;
                const int rowb = wn * 64 + t * 16 + nlow;
                const int ca = (kc * 4 + quad) ^ (nlow & 7);
                af[t]  = load8(&As[cur][(rowa * 8 + ca) * 8]);
                bfr[t] = load8(&Bs[cur][(rowb * 8 + ca) * 8]);
            }
#pragma unroll
            for (int t = 0; t < 4; t++)
#pragma unroll
                for (int g = 0; g < 4; g++)
                    acc[t][g] = MFMA16(af[t], bfr[g], acc[t][g]);
        }
        if (more) {
#pragma unroll
            for (int i = 0; i < 4; i++)
                cvt_write8(&Bs[cur ^ 1][sw[i]], rw[i][0], rw[i][1]);
        }
        __syncthreads();
        cur ^= 1;
    }

#pragma unroll
    for (int g = 0; g < 4; g++) {
        const int j = col0 + wn * 64 + g * 16 + nlow;
        const float bj = bo[j];
#pragma unroll
        for (int t = 0; t < 4; t++) {
#pragma unroll
            for (int r = 0; r < 4; r++) {
                const int i = row0 + wm * 64 + t * 16 + quad * 4 + r;
                outp[(long)i * 512 + j] = acc[t][g][r] + bj;
            }
        }
    }
}

// ---------------------------------------------------------------------------
// Flash attention, fixed-offset softmax (unchanged from round 2 — verified).
//   * 64-key tiles, double-buffered K/V, ONE __syncthreads per tile.
//   * async-STAGE split; K via global_load_lds with pre-swizzled source;
//     Vt/Ps XOR-swizzled unpadded LDS (40960 B -> 4 blocks/CU).
//   * XCD-aware grid: h = f&7 -> one head per XCD, all batches per XCD.
// qp/kp/vp: [B,H,S,64] bf16. out: [B,S,512] bf16.
// ---------------------------------------------------------------------------
__device__ __forceinline__ int ks_idx(int key, int dchunk) {
    return key * 64 + ((dchunk ^ (key & 7)) << 3);
}
__device__ __forceinline__ int vt_idx(int key, int dh) {
    return dh * 64 + ((((key >> 3) ^ (dh & 7) ^ ((dh >> 3) & 7)) << 3) + (key & 7));
}
__device__ __forceinline__ int ps_idx(int q, int key) {
    return q * 64 + ((((key >> 3) ^ (q & 7)) << 3) + (key & 7));
}

__global__ __launch_bounds__(256, 4)
void attn_kernel(const unsigned short* __restrict__ qp,
                 const unsigned short* __restrict__ kp,
                 const unsigned short* __restrict__ vp,
                 const void* __restrict__ masked,
                 unsigned short* __restrict__ out)
{
    __shared__ unsigned short Ks[2][4096];   // [buf][key*64 + swz_chunk*8+e]
    __shared__ unsigned short Vt[2][4096];   // [buf][dh*64 + swz_col]
    __shared__ unsigned short Ps[4][1024];   // [wave][q*64 + swz_chunk*8+e]

    const int tid  = threadIdx.x;
    const int lane = tid & 63;
    const int w    = tid >> 6;
    const int quad = lane >> 4;
    const int nlow = lane & 15;

    const int f  = blockIdx.x;          // 0..1023
    const int h  = f & 7;
    const int qb = (f >> 3) & 31;
    const int b  = f >> 8;
    const int q0 = qb * 64 + w * 16;
    const long base = ((long)(b * 8 + h)) * 2048 * 64;

    const long long first = *reinterpret_cast<const long long*>(masked);
    int kmax;
    if ((first >> 32) != 0) kmax = reinterpret_cast<const int*>(masked)[b];
    else                    kmax = (int)reinterpret_cast<const long long*>(masked)[b];
    kmax = min(max(kmax, 1), 2048);
    const int nkt = (kmax + 63) >> 6;

    const unsigned short* qrow = qp + base + (long)(q0 + nlow) * 64;
    const short8 aq0 = load8(qrow + quad * 8);
    const short8 aq1 = load8(qrow + 32 + quad * 8);

    short8 ones;
#pragma unroll
    for (int j = 0; j < 8; j++) ones[j] = (short)0x3F80;

    f32x4 o_acc[4], lacc;
#pragma unroll
    for (int vb = 0; vb < 4; vb++) o_acc[vb] = (f32x4){0.f, 0.f, 0.f, 0.f};
    lacc = (f32x4){0.f, 0.f, 0.f, 0.f};

    const int kr0 = tid >> 3;
    const int kr1 = 32 + kr0;
    const unsigned short* kg0 = kp + base + (long)kr0 * 64 + (((tid & 7) ^ (kr0 & 7)) << 3);
    const unsigned short* kg1 = kp + base + (long)kr1 * 64 + (((tid & 7) ^ (kr1 & 7)) << 3);
    const int kd0 = (w << 9);
    const int kd1 = 2048 + (w << 9);
    const int vk0 = tid >> 3;
    const int vk1 = 32 + vk0;
    const int vd0 = (tid & 7) << 3;
    const unsigned short* vg0 = vp + base + (long)vk0 * 64 + vd0;
    const unsigned short* vg1 = vp + base + (long)vk1 * 64 + vd0;

    gload_lds16(kg0, &Ks[0][kd0]);
    gload_lds16(kg1, &Ks[0][kd1]);
    {
        short8 v0 = load8(vg0);
        short8 v1 = load8(vg1);
#pragma unroll
        for (int j = 0; j < 8; j++) {
            Vt[0][vt_idx(vk0, vd0 + j)] = (unsigned short)v0[j];
            Vt[0][vt_idx(vk1, vd0 + j)] = (unsigned short)v1[j];
        }
    }
    __syncthreads();

    unsigned short* Psw = Ps[w];
    int cur = 0;
    short8 vv0, vv1;

    for (int kt = 0; kt < nkt; kt++) {
        const int k0 = kt * 64;
        const bool more = (kt + 1 < nkt);   // block-uniform
        if (more) {
            const long off = (long)(k0 + 64) * 64;
            gload_lds16(kg0 + off, &Ks[cur ^ 1][kd0]);
            gload_lds16(kg1 + off, &Ks[cur ^ 1][kd1]);
            vv0 = load8(vg0 + off);
            vv1 = load8(vg1 + off);
        }
        const unsigned short* Ksc = Ks[cur];
        const unsigned short* Vtc = Vt[cur];

        f32x4 sacc[4];
#pragma unroll
        for (int kb = 0; kb < 4; kb++) sacc[kb] = (f32x4){0.f, 0.f, 0.f, 0.f};
#pragma unroll
        for (int kb = 0; kb < 4; kb++) {
            const int key = kb * 16 + nlow;
            short8 bk0 = load8(Ksc + ks_idx(key, quad));
            short8 bk1 = load8(Ksc + ks_idx(key, 4 + quad));
            sacc[kb] = MFMA16(aq0, bk0, sacc[kb]);
            sacc[kb] = MFMA16(aq1, bk1, sacc[kb]);
        }

#pragma unroll
        for (int kb = 0; kb < 4; kb++) {
            const bool valid = (k0 + kb * 16 + nlow) < kmax;
#pragma unroll
            for (int r = 0; r < 4; r++) {
                const int q = quad * 4 + r;
                const float e = valid ? fmaf(sacc[kb][r], SCALE_LOG2, -FIXED_M)
                                      : MASKED_E2;
                Psw[ps_idx(q, kb * 16 + nlow)] = f2bf(exp2f(e));
            }
        }
        __threadfence_block();

#pragma unroll
        for (int h2 = 0; h2 < 2; h2++) {
            const int g = h2 * 4 + quad;
            short8 ap = load8(Psw + ps_idx(nlow, g << 3));
            lacc = MFMA16(ap, ones, lacc);
#pragma unroll
            for (int vb = 0; vb < 4; vb++) {
                short8 bv = load8(Vtc + vt_idx(g << 3, vb * 16 + nlow));
                o_acc[vb] = MFMA16(ap, bv, o_acc[vb]);
            }
        }

        if (more) {
            unsigned short* Vtn = Vt[cur ^ 1];
#pragma unroll
            for (int j = 0; j < 8; j++) {
                Vtn[vt_idx(vk0, vd0 + j)] = (unsigned short)vv0[j];
                Vtn[vt_idx(vk1, vd0 + j)] = (unsigned short)vv1[j];
            }
        }
        __syncthreads();
        cur ^= 1;
    }

    float inv_l[4];
#pragma unroll
    for (int r = 0; r < 4; r++) inv_l[r] = 1.0f / lacc[r];
#pragma unroll
    for (int vb = 0; vb < 4; vb++) {
#pragma unroll
        for (int r = 0; r < 4; r++) {
            const int s   = q0 + quad * 4 + r;
            const int col = h * 64 + vb * 16 + nlow;
            out[(long)(b * 2048 + s) * 512 + col] = f2bf(o_acc[vb][r] * inv_l[r]);
        }
    }
}

// ---------------------------------------------------------------------------
// ws layout (u16 elems):
//   [0)          qp,kp,vp  3 x 4194304
//   [12582912)   ao        4194304
// total 16.8M u16 = 33.5 MB
// ---------------------------------------------------------------------------
extern "C" void kernel_launch(void* const* d_in, const int* in_sizes, int n_in,
                              void* d_out, int out_size, void* d_ws, size_t ws_size,
                              hipStream_t stream)
{
    const float* Q  = (const float*)d_in[0];
    const float* K  = (const float*)d_in[1];
    const float* V  = (const float*)d_in[2];
    const float* Wq = (const float*)d_in[3];
    const float* bq = (const float*)d_in[4];
    const float* Wk = (const float*)d_in[5];
    const float* bk = (const float*)d_in[6];
    const float* Wv = (const float*)d_in[7];
    const float* bv = (const float*)d_in[8];
    const float* Wo = (const float*)d_in[9];
    const float* bo = (const float*)d_in[10];
    const void*  masked = d_in[11];

    unsigned short* ws16 = (unsigned short*)d_ws;
    unsigned short* qp = ws16;
    unsigned short* kp = qp + 4194304;
    unsigned short* vp = kp + 4194304;
    unsigned short* ao = vp + 4194304;

    gemm_qkv<<<dim3(256, 3), 256, 0, stream>>>(Q, K, V, Wq, Wk, Wv, bq, bk, bv, qp);
    attn_kernel<<<dim3(1024), 256, 0, stream>>>(qp, kp, vp, masked, ao);
    gemm_out<<<dim3(256), 256, 0, stream>>>(ao, Wo, bo, (float*)d_out);
}